// Round 1
// baseline (476.913 us; speedup 1.0000x reference)
//
#include <hip/hip_runtime.h>
#include <math.h>

#define NBOX 1024
#define PI_F 3.141592653f
#define TWO_PI_F 6.283185306f
#define HALF_PI_F 1.5707963265f
#define IOU_THR_F 0.3f

__device__ __forceinline__ float limit_period_f(float v) {
    return v - floorf(v / TWO_PI_F + 0.5f) * TWO_PI_F;
}

// ---------------------------------------------------------------------------
// Clip polygon (px,py,cnt) by half-plane left of edge (a->b).
// Fully unrolled, register-only (no runtime-indexed array writes).
// Mirrors the reference's emit ordering: per input vertex v: [p1 if in1,
// intersection if in1^in2], valid = v < cnt, t = d1/denom guarded at 1e-8.
// ---------------------------------------------------------------------------
__device__ __forceinline__ void clip_edge(float (&px)[8], float (&py)[8], int &cnt,
                                          float axp, float ayp, float bxp, float byp) {
    float ex = bxp - axp, ey = byp - ayp;
    float d[8];
#pragma unroll
    for (int v = 0; v < 8; ++v)
        d[v] = ex * (py[v] - ayp) - ey * (px[v] - axp);

    float cxv[16], cyv[16];
    bool fl[16];
#pragma unroll
    for (int v = 0; v < 8; ++v) {
        bool valid = v < cnt;
        bool wrap = !(v + 1 < cnt);              // reference: nxt = idx+1<cnt ? idx+1 : 0
        float p2x = wrap ? px[0] : px[(v + 1) & 7];
        float p2y = wrap ? py[0] : py[(v + 1) & 7];
        float d2v = wrap ? d[0] : d[(v + 1) & 7];
        float d1v = d[v];
        bool in1 = d1v >= 0.0f, in2 = d2v >= 0.0f;
        fl[2 * v] = in1 && valid;
        cxv[2 * v] = px[v];
        cyv[2 * v] = py[v];
        fl[2 * v + 1] = (in1 != in2) && valid;
        float den = d1v - d2v;
        float t = d1v / (fabsf(den) > 1e-8f ? den : 1.0f);
        cxv[2 * v + 1] = px[v] + t * (p2x - px[v]);
        cyv[2 * v + 1] = py[v] + t * (p2y - py[v]);
    }

    // Compact candidates into output slots with an unrolled select network.
    int pos = 0;
    float ox[8], oy[8];
#pragma unroll
    for (int o = 0; o < 8; ++o) { ox[o] = 0.0f; oy[o] = 0.0f; }
#pragma unroll
    for (int c = 0; c < 16; ++c) {
#pragma unroll
        for (int o = 0; o < 8; ++o) {
            if (o > c) continue;                 // pos[c] <= c, compile-time prune
            if (fl[c] && pos == o) { ox[o] = cxv[c]; oy[o] = cyv[c]; }
        }
        pos += fl[c] ? 1 : 0;
    }
    cnt = pos > 8 ? 8 : pos;
#pragma unroll
    for (int v = 0; v < 8; ++v) { px[v] = ox[v]; py[v] = oy[v]; }
}

// ---------------------------------------------------------------------------
// Kernel 1: pairwise IoU3D > 0.3 adjacency bitmask. One thread per (i,j);
// wave = 64 consecutive j for one i -> one u64 adjacency word per wave.
// ---------------------------------------------------------------------------
__global__ __launch_bounds__(256) void iou_adj_kernel(const float* __restrict__ boxes,
                                                      unsigned long long* __restrict__ adj) {
    int t = blockIdx.x * 256 + threadIdx.x;
    int i = t >> 10;
    int j = t & 1023;
    const float* ba = boxes + i * 7;
    const float* bb = boxes + j * 7;
    float ax = ba[0], ay = ba[1], az = ba[2], al = ba[3], aw = ba[4], ah = ba[5];
    float bx = bb[0], by = bb[1], bz = bb[2], bl = bb[3], bw = bb[4], bh = bb[5];
    float tha = limit_period_f(ba[6]);
    float thb = limit_period_f(bb[6]);

    bool hit = false;
    float dx = ax - bx, dy = ay - by;
    float ra = 0.5f * sqrtf(al * al + aw * aw);
    float rb = 0.5f * sqrtf(bl * bl + bw * bw);
    float top = fminf(az + 0.5f * ah, bz + 0.5f * bh);
    float bot = fmaxf(az - 0.5f * ah, bz - 0.5f * bh);
    float hov = fmaxf(top - bot, 0.0f);
    float rr = ra + rb;
    // Exact reject: disjoint circumscribed circles or no height overlap => iou = 0.
    if (dx * dx + dy * dy <= rr * rr && hov > 0.0f) {
        float ca = __cosf(0.0f), sa; // placeholders, overwritten below (avoid fast approx)
        ca = cosf(tha); sa = sinf(tha);
        float cb = cosf(thb), sb = sinf(thb);

        float px[8], py[8];
        {   // corners of A: signs (0.5,-0.5),(0.5,0.5),(-0.5,0.5),(-0.5,-0.5)
            float hx = 0.5f * al, hy = 0.5f * aw;
            float sxv[4] = { hx, hx, -hx, -hx };
            float syv[4] = { -hy, hy, hy, -hy };
#pragma unroll
            for (int k = 0; k < 4; ++k) {
                px[k] = sxv[k] * ca - syv[k] * sa + ax;
                py[k] = sxv[k] * sa + syv[k] * ca + ay;
            }
#pragma unroll
            for (int k = 4; k < 8; ++k) { px[k] = 0.0f; py[k] = 0.0f; }
        }
        float qx[4], qy[4];
        {
            float hx = 0.5f * bl, hy = 0.5f * bw;
            float sxv[4] = { hx, hx, -hx, -hx };
            float syv[4] = { -hy, hy, hy, -hy };
#pragma unroll
            for (int k = 0; k < 4; ++k) {
                qx[k] = sxv[k] * cb - syv[k] * sb + bx;
                qy[k] = sxv[k] * sb + syv[k] * cb + by;
            }
        }
        int cnt = 4;
#pragma unroll
        for (int k = 0; k < 4; ++k)
            clip_edge(px, py, cnt, qx[k], qy[k], qx[(k + 1) & 3], qy[(k + 1) & 3]);

        // shoelace area over cnt vertices
        float s2 = 0.0f;
#pragma unroll
        for (int v = 0; v < 8; ++v) {
            bool valid = v < cnt;
            bool wrap = !(v + 1 < cnt);
            float p2x = wrap ? px[0] : px[(v + 1) & 7];
            float p2y = wrap ? py[0] : py[(v + 1) & 7];
            float cr = px[v] * p2y - p2x * py[v];
            s2 += valid ? cr : 0.0f;
        }
        float area = 0.5f * fabsf(s2);
        float inter = area * hov;
        float va = al * aw * ah, vb = bl * bw * bh;
        float iou = inter / fmaxf(va + vb - inter, 1e-6f);
        hit = iou > IOU_THR_F;
    }
    unsigned long long bal = __ballot(hit);
    if ((threadIdx.x & 63) == 0)
        adj[t >> 6] = bal;
}

// ---------------------------------------------------------------------------
// Kernel 2: sequential greedy clustering (exact reference semantics incl.
// reassignment of already-assigned boxes). Single wave; lane l owns boxes
// l*16..l*16+15; unassigned set + cluster ids live in registers.
// ---------------------------------------------------------------------------
__global__ void cluster_kernel(const unsigned long long* __restrict__ adj,
                               int* __restrict__ ci) {
    int lane = threadIdx.x;          // 64 threads
    int cival[16];
#pragma unroll
    for (int k = 0; k < 16; ++k) cival[k] = 0;
    unsigned int um = 0xFFFFu;       // 16 boxes, all unassigned
    int cur = 1;
    while (true) {
        unsigned long long bal = __ballot(um != 0u);
        if (bal == 0ull) break;
        int fl = __ffsll((long long)bal) - 1;
        int fb = __ffs(um) - 1;                  // valid on lanes with um != 0
        int bit = __shfl(fb, fl);
        int first = fl * 16 + bit;
        unsigned long long word = adj[first * 16 + (lane >> 2)];
        unsigned int bits = (unsigned int)(word >> ((lane & 3) * 16)) & 0xFFFFu;
#pragma unroll
        for (int k = 0; k < 16; ++k)
            if (bits & (1u << k)) cival[k] = cur;   // reassignment allowed
        um &= ~bits;
        ++cur;
    }
#pragma unroll
    for (int k = 0; k < 16; ++k)
        ci[lane * 16 + k] = cival[k];
}

// ---------------------------------------------------------------------------
// Kernel 3: cluster fusion. Block = 256 threads = 4 waves; wave w handles
// cid = blockIdx*4 + w + 1. Boxes (heading limited), scores, ci in LDS.
// Three passes mirror the reference exactly.
// ---------------------------------------------------------------------------
__global__ __launch_bounds__(256) void fusion_kernel(const float* __restrict__ boxes,
                                                     const float* __restrict__ scores,
                                                     const int* __restrict__ ci,
                                                     float* __restrict__ out) {
    __shared__ float sb[NBOX][7];
    __shared__ float ss[NBOX];
    __shared__ int   sc[NBOX];
    int tid = threadIdx.x;
    for (int idx = tid; idx < NBOX * 7; idx += 256) {
        float v = boxes[idx];
        int col = idx % 7;
        if (col == 6) v = limit_period_f(v);
        sb[idx / 7][col] = v;
    }
    for (int b = tid; b < NBOX; b += 256) {
        ss[b] = scores[b];
        sc[b] = ci[b];
    }
    __syncthreads();

    int wave = tid >> 6;
    int lane = tid & 63;
    int cid = blockIdx.x * 4 + wave + 1;

    // ---- pass 1: argmax of masked scores (first occurrence on ties) ----
    float bv = -INFINITY;
    int bi = 0;
    for (int c = 0; c < 16; ++c) {
        int b = c * 64 + lane;
        float v = (sc[b] == cid) ? ss[b] : -INFINITY;
        if (v > bv) { bv = v; bi = b; }          // ascending b => keeps first max
    }
#pragma unroll
    for (int off = 32; off > 0; off >>= 1) {
        float ov = __shfl_xor(bv, off);
        int   oi = __shfl_xor(bi, off);
        if (ov > bv || (ov == bv && oi < bi)) { bv = ov; bi = oi; }
    }
    float d0 = sb[bi][6];

    // ---- pass 2: flip decision + score sum ----
    float sgt = 0.0f, sngt = 0.0f, ssum = 0.0f;
    for (int c = 0; c < 16; ++c) {
        int b = c * 64 + lane;
        float s = (sc[b] == cid) ? ss[b] : 0.0f;
        float diff = fabsf(sb[b][6] - d0);
        diff = (diff > PI_F) ? (TWO_PI_F - diff) : diff;
        bool gt = diff > HALF_PI_F;
        sgt += gt ? s : 0.0f;
        sngt += gt ? 0.0f : s;
        ssum += s;
    }
#pragma unroll
    for (int off = 32; off > 0; off >>= 1) {
        sgt  += __shfl_xor(sgt, off);
        sngt += __shfl_xor(sngt, off);
        ssum += __shfl_xor(ssum, off);
    }
    bool flip = (sgt <= sngt);
    bool valid = ssum > 0.0f;
    float inv = valid ? ssum : 1.0f;

    // ---- pass 3: weighted sums (sn applied per-box like the reference) ----
    float sint = 0.0f, cost = 0.0f;
    float acc[6] = { 0.0f, 0.0f, 0.0f, 0.0f, 0.0f, 0.0f };
    for (int c = 0; c < 16; ++c) {
        int b = c * 64 + lane;
        float s = (sc[b] == cid) ? ss[b] : 0.0f;
        float sn = s / inv;
        float dH = sb[b][6];
        float diff = fabsf(dH - d0);
        diff = (diff > PI_F) ? (TWO_PI_F - diff) : diff;
        bool gt = diff > HALF_PI_F;
        bool cond = flip ? gt : !gt;
        float dd = cond ? (dH + PI_F) : dH;
        dd = limit_period_f(dd);
        sint += sinf(dd) * sn;
        cost += cosf(dd) * sn;
#pragma unroll
        for (int jj = 0; jj < 6; ++jj)
            acc[jj] += sb[b][jj] * sn;
    }
#pragma unroll
    for (int off = 32; off > 0; off >>= 1) {
        sint += __shfl_xor(sint, off);
        cost += __shfl_xor(cost, off);
#pragma unroll
        for (int jj = 0; jj < 6; ++jj)
            acc[jj] += __shfl_xor(acc[jj], off);
    }

    if (lane == 0) {
        float* o = out + (cid - 1) * 7;
        if (valid) {
#pragma unroll
            for (int jj = 0; jj < 6; ++jj) o[jj] = acc[jj];
            o[6] = atan2f(sint, cost);
        } else {
#pragma unroll
            for (int jj = 0; jj < 7; ++jj) o[jj] = 0.0f;
        }
    }
}

extern "C" void kernel_launch(void* const* d_in, const int* in_sizes, int n_in,
                              void* d_out, int out_size, void* d_ws, size_t ws_size,
                              hipStream_t stream) {
    const float* boxes  = (const float*)d_in[0];   // (1024,7) f32
    const float* scores = (const float*)d_in[1];   // (1024,)  f32
    unsigned long long* adj = (unsigned long long*)d_ws;              // 1024*16 u64 = 128 KB
    int* ci = (int*)((char*)d_ws + (size_t)NBOX * 16 * sizeof(unsigned long long));
    float* out = (float*)d_out;                    // (1024,7) f32

    iou_adj_kernel<<<(NBOX * NBOX) / 256, 256, 0, stream>>>(boxes, adj);
    cluster_kernel<<<1, 64, 0, stream>>>(adj, ci);
    fusion_kernel<<<NBOX / 4, 256, 0, stream>>>(boxes, scores, ci, out);
}

// Round 3
// 282.455 us; speedup vs baseline: 1.6885x; 1.6885x over previous
//
#include <hip/hip_runtime.h>
#include <math.h>

#define NBOX 1024
#define PI_F 3.141592653f
#define TWO_PI_F 6.283185306f
#define HALF_PI_F 1.5707963265f
#define IOU_THR_F 0.3f

__device__ __forceinline__ float limit_period_f(float v) {
    return v - floorf(v / TWO_PI_F + 0.5f) * TWO_PI_F;
}

// ---------------------------------------------------------------------------
// Clip polygon (px,py,cnt) by half-plane left of edge (a->b).
// Fully unrolled, register-only (no runtime-indexed array writes).
// ---------------------------------------------------------------------------
__device__ __forceinline__ void clip_edge(float (&px)[8], float (&py)[8], int &cnt,
                                          float axp, float ayp, float bxp, float byp) {
    float ex = bxp - axp, ey = byp - ayp;
    float d[8];
#pragma unroll
    for (int v = 0; v < 8; ++v)
        d[v] = ex * (py[v] - ayp) - ey * (px[v] - axp);

    float cxv[16], cyv[16];
    bool fl[16];
#pragma unroll
    for (int v = 0; v < 8; ++v) {
        bool valid = v < cnt;
        bool wrap = !(v + 1 < cnt);              // reference: nxt = idx+1<cnt ? idx+1 : 0
        float p2x = wrap ? px[0] : px[(v + 1) & 7];
        float p2y = wrap ? py[0] : py[(v + 1) & 7];
        float d2v = wrap ? d[0] : d[(v + 1) & 7];
        float d1v = d[v];
        bool in1 = d1v >= 0.0f, in2 = d2v >= 0.0f;
        fl[2 * v] = in1 && valid;
        cxv[2 * v] = px[v];
        cyv[2 * v] = py[v];
        fl[2 * v + 1] = (in1 != in2) && valid;
        float den = d1v - d2v;
        float t = d1v / (fabsf(den) > 1e-8f ? den : 1.0f);
        cxv[2 * v + 1] = px[v] + t * (p2x - px[v]);
        cyv[2 * v + 1] = py[v] + t * (p2y - py[v]);
    }

    // Compact candidates into output slots with an unrolled select network.
    int pos = 0;
    float ox[8], oy[8];
#pragma unroll
    for (int o = 0; o < 8; ++o) { ox[o] = 0.0f; oy[o] = 0.0f; }
#pragma unroll
    for (int c = 0; c < 16; ++c) {
#pragma unroll
        for (int o = 0; o < 8; ++o) {
            if (o > c) continue;                 // pos[c] <= c, compile-time prune
            if (fl[c] && pos == o) { ox[o] = cxv[c]; oy[o] = cyv[c]; }
        }
        pos += fl[c] ? 1 : 0;
    }
    cnt = pos > 8 ? 8 : pos;
#pragma unroll
    for (int v = 0; v < 8; ++v) { px[v] = ox[v]; py[v] = oy[v]; }
}

// ---------------------------------------------------------------------------
// Kernel 1: pairwise IoU3D > 0.3 adjacency bitmask. One thread per (i,j);
// wave = 64 consecutive j for one i -> one u64 adjacency word per wave.
// ---------------------------------------------------------------------------
__global__ __launch_bounds__(256) void iou_adj_kernel(const float* __restrict__ boxes,
                                                      unsigned long long* __restrict__ adj) {
    int t = blockIdx.x * 256 + threadIdx.x;
    int i = t >> 10;
    int j = t & 1023;
    const float* ba = boxes + i * 7;
    const float* bb = boxes + j * 7;
    float ax = ba[0], ay = ba[1], az = ba[2], al = ba[3], aw = ba[4], ah = ba[5];
    float bx = bb[0], by = bb[1], bz = bb[2], bl = bb[3], bw = bb[4], bh = bb[5];
    float tha = limit_period_f(ba[6]);
    float thb = limit_period_f(bb[6]);

    bool hit = false;
    float dx = ax - bx, dy = ay - by;
    float ra = 0.5f * sqrtf(al * al + aw * aw);
    float rb = 0.5f * sqrtf(bl * bl + bw * bw);
    float top = fminf(az + 0.5f * ah, bz + 0.5f * bh);
    float bot = fmaxf(az - 0.5f * ah, bz - 0.5f * bh);
    float hov = fmaxf(top - bot, 0.0f);
    float rr = ra + rb;
    // Exact reject: disjoint circumscribed circles or no height overlap => iou = 0.
    if (dx * dx + dy * dy <= rr * rr && hov > 0.0f) {
        float ca = cosf(tha), sa = sinf(tha);
        float cb = cosf(thb), sb = sinf(thb);

        float px[8], py[8];
        {   // corners of A: signs (0.5,-0.5),(0.5,0.5),(-0.5,0.5),(-0.5,-0.5)
            float hx = 0.5f * al, hy = 0.5f * aw;
            float sxv[4] = { hx, hx, -hx, -hx };
            float syv[4] = { -hy, hy, hy, -hy };
#pragma unroll
            for (int k = 0; k < 4; ++k) {
                px[k] = sxv[k] * ca - syv[k] * sa + ax;
                py[k] = sxv[k] * sa + syv[k] * ca + ay;
            }
#pragma unroll
            for (int k = 4; k < 8; ++k) { px[k] = 0.0f; py[k] = 0.0f; }
        }
        float qx[4], qy[4];
        {
            float hx = 0.5f * bl, hy = 0.5f * bw;
            float sxv[4] = { hx, hx, -hx, -hx };
            float syv[4] = { -hy, hy, hy, -hy };
#pragma unroll
            for (int k = 0; k < 4; ++k) {
                qx[k] = sxv[k] * cb - syv[k] * sb + bx;
                qy[k] = sxv[k] * sb + syv[k] * cb + by;
            }
        }
        int cnt = 4;
#pragma unroll
        for (int k = 0; k < 4; ++k)
            clip_edge(px, py, cnt, qx[k], qy[k], qx[(k + 1) & 3], qy[(k + 1) & 3]);

        // shoelace area over cnt vertices
        float s2 = 0.0f;
#pragma unroll
        for (int v = 0; v < 8; ++v) {
            bool valid = v < cnt;
            bool wrap = !(v + 1 < cnt);
            float p2x = wrap ? px[0] : px[(v + 1) & 7];
            float p2y = wrap ? py[0] : py[(v + 1) & 7];
            float cr = px[v] * p2y - p2x * py[v];
            s2 += valid ? cr : 0.0f;
        }
        float area = 0.5f * fabsf(s2);
        float inter = area * hov;
        float va = al * aw * ah, vb = bl * bw * bh;
        float iou = inter / fmaxf(va + vb - inter, 1e-6f);
        hit = iou > IOU_THR_F;
    }
    unsigned long long bal = __ballot(hit);
    if ((threadIdx.x & 63) == 0)
        adj[t >> 6] = bal;
}

// ---------------------------------------------------------------------------
// Kernel 2: sequential greedy clustering, restructured as an ordered scan.
// Since the unassigned set only loses bits, the reference's
// "first = argmax(unassigned)" sequence is strictly increasing -> scan
// r = 0..1023; r is a seed iff its bit is still set. Adjacency-row loads are
// unconditional at static addresses -> software-pipelined 8 deep, OUT of the
// serial chain. Lane l owns 16-bit slice l of each row word (boxes 16l..16l+15)
// so the seed test is one v_cmp + __ballot (no shfl, no LDS in the chain).
// Publishes n_clusters to nclust_out for the fusion kernel's early exit.
// ---------------------------------------------------------------------------
__global__ void cluster_kernel(const unsigned long long* __restrict__ adj,
                               int* __restrict__ ci,
                               int* __restrict__ nclust_out) {
    int lane = threadIdx.x;          // 64 threads
    int widx = lane >> 2;            // which u64 word of a row this lane reads
    int shft = (lane & 3) * 16;      // 16-bit subfield within that word
    const unsigned long long* rp = adj + widx;

    int cival[16];
#pragma unroll
    for (int k = 0; k < 16; ++k) cival[k] = 0;
    unsigned int um = 0xFFFFu;       // unassigned bits for this lane's 16 boxes
    int cur = 1;

    unsigned long long p[8];
#pragma unroll
    for (int d = 0; d < 8; ++d) p[d] = rp[d * 16];

    for (int r = 0; r < NBOX; r += 8) {
#pragma unroll
        for (int d = 0; d < 8; ++d) {
            unsigned long long w = p[d];
            int nr = r + 8 + d;                       // prefetch 8 rows ahead
            p[d] = (nr < NBOX) ? rp[nr * 16] : 0ull;
            int rr = r + d;
            bool own = (lane == (rr >> 4));
            unsigned long long bal = __ballot(own && ((um >> (rr & 15)) & 1u));
            if (bal) {                                // wave-uniform: rr is a seed
                unsigned int bits = (unsigned int)(w >> shft) & 0xFFFFu;
#pragma unroll
                for (int k = 0; k < 16; ++k)
                    if (bits & (1u << k)) cival[k] = cur;   // reassignment allowed
                um &= ~bits;
                ++cur;
            }
        }
    }
#pragma unroll
    for (int k = 0; k < 16; ++k)
        ci[lane * 16 + k] = cival[k];
    if (lane == 0)
        *nclust_out = cur - 1;       // number of non-empty cluster ids
}

// ---------------------------------------------------------------------------
// Kernel 3: cluster fusion. Block = 256 threads = 4 waves; wave w handles
// cid = blockIdx*4 + w + 1. Boxes (heading limited), scores, ci in LDS.
// Block-level early exit when all 4 cids exceed n_clusters (block-uniform,
// skips the 36 KB LDS staging); per-wave early exit for empty cids otherwise.
// Three passes mirror the reference exactly.
// ---------------------------------------------------------------------------
__global__ __launch_bounds__(256) void fusion_kernel(const float* __restrict__ boxes,
                                                     const float* __restrict__ scores,
                                                     const int* __restrict__ ci,
                                                     const int* __restrict__ nclust_p,
                                                     float* __restrict__ out) {
    __shared__ float sb[NBOX][7];
    __shared__ float ss[NBOX];
    __shared__ int   sc[NBOX];
    int tid = threadIdx.x;
    int nclust = *nclust_p;                       // block-uniform scalar load

    if (blockIdx.x * 4 + 1 > nclust) {            // all 4 cids empty: zero rows, skip staging
        if (tid < 28) {
            out[blockIdx.x * 28 + tid] = 0.0f;    // 4 cids x 7 floats
        }
        return;
    }

    for (int idx = tid; idx < NBOX * 7; idx += 256) {
        float v = boxes[idx];
        int col = idx % 7;
        if (col == 6) v = limit_period_f(v);
        sb[idx / 7][col] = v;
    }
    for (int b = tid; b < NBOX; b += 256) {
        ss[b] = scores[b];
        sc[b] = ci[b];
    }
    __syncthreads();

    int wave = tid >> 6;
    int lane = tid & 63;
    int cid = blockIdx.x * 4 + wave + 1;

    // ---- pass 1: argmax of masked scores (first occurrence on ties) ----
    float bv = -INFINITY;
    int bi = 0;
    for (int c = 0; c < 16; ++c) {
        int b = c * 64 + lane;
        float v = (sc[b] == cid) ? ss[b] : -INFINITY;
        if (v > bv) { bv = v; bi = b; }          // ascending b => keeps first max
    }
#pragma unroll
    for (int off = 32; off > 0; off >>= 1) {
        float ov = __shfl_xor(bv, off);
        int   oi = __shfl_xor(bi, off);
        if (ov > bv || (ov == bv && oi < bi)) { bv = ov; bi = oi; }
    }
    float* o = out + (cid - 1) * 7;
    if (!(bv > -INFINITY)) {                     // empty cluster: all-zero row
        if (lane == 0) {
#pragma unroll
            for (int jj = 0; jj < 7; ++jj) o[jj] = 0.0f;
        }
        return;
    }
    float d0 = sb[bi][6];

    // ---- pass 2: flip decision + score sum ----
    float sgt = 0.0f, sngt = 0.0f, ssum = 0.0f;
    for (int c = 0; c < 16; ++c) {
        int b = c * 64 + lane;
        float s = (sc[b] == cid) ? ss[b] : 0.0f;
        float diff = fabsf(sb[b][6] - d0);
        diff = (diff > PI_F) ? (TWO_PI_F - diff) : diff;
        bool gt = diff > HALF_PI_F;
        sgt += gt ? s : 0.0f;
        sngt += gt ? 0.0f : s;
        ssum += s;
    }
#pragma unroll
    for (int off = 32; off > 0; off >>= 1) {
        sgt  += __shfl_xor(sgt, off);
        sngt += __shfl_xor(sngt, off);
        ssum += __shfl_xor(ssum, off);
    }
    bool flip = (sgt <= sngt);
    float inv = ssum;                            // non-empty => ssum > 0

    // ---- pass 3: weighted sums (sn applied per-box like the reference) ----
    float sint = 0.0f, cost = 0.0f;
    float acc[6] = { 0.0f, 0.0f, 0.0f, 0.0f, 0.0f, 0.0f };
    for (int c = 0; c < 16; ++c) {
        int b = c * 64 + lane;
        float s = (sc[b] == cid) ? ss[b] : 0.0f;
        float sn = s / inv;
        float dH = sb[b][6];
        float diff = fabsf(dH - d0);
        diff = (diff > PI_F) ? (TWO_PI_F - diff) : diff;
        bool gt = diff > HALF_PI_F;
        bool cond = flip ? gt : !gt;
        float dd = cond ? (dH + PI_F) : dH;
        dd = limit_period_f(dd);
        sint += sinf(dd) * sn;
        cost += cosf(dd) * sn;
#pragma unroll
        for (int jj = 0; jj < 6; ++jj)
            acc[jj] += sb[b][jj] * sn;
    }
#pragma unroll
    for (int off = 32; off > 0; off >>= 1) {
        sint += __shfl_xor(sint, off);
        cost += __shfl_xor(cost, off);
#pragma unroll
        for (int jj = 0; jj < 6; ++jj)
            acc[jj] += __shfl_xor(acc[jj], off);
    }

    if (lane == 0) {
#pragma unroll
        for (int jj = 0; jj < 6; ++jj) o[jj] = acc[jj];
        o[6] = atan2f(sint, cost);
    }
}

extern "C" void kernel_launch(void* const* d_in, const int* in_sizes, int n_in,
                              void* d_out, int out_size, void* d_ws, size_t ws_size,
                              hipStream_t stream) {
    const float* boxes  = (const float*)d_in[0];   // (1024,7) f32
    const float* scores = (const float*)d_in[1];   // (1024,)  f32
    unsigned long long* adj = (unsigned long long*)d_ws;              // 1024*16 u64 = 128 KB
    int* ci = (int*)((char*)d_ws + (size_t)NBOX * 16 * sizeof(unsigned long long));
    int* nclust = ci + NBOX;                       // one int after ci
    float* out = (float*)d_out;                    // (1024,7) f32

    iou_adj_kernel<<<(NBOX * NBOX) / 256, 256, 0, stream>>>(boxes, adj);
    cluster_kernel<<<1, 64, 0, stream>>>(adj, ci, nclust);
    fusion_kernel<<<NBOX / 4, 256, 0, stream>>>(boxes, scores, ci, nclust, out);
}

// Round 4
// 254.758 us; speedup vs baseline: 1.8720x; 1.1087x over previous
//
#include <hip/hip_runtime.h>
#include <math.h>

#define NBOX 1024
#define PI_F 3.141592653f
#define TWO_PI_F 6.283185306f
#define HALF_PI_F 1.5707963265f
#define IOU_THR_F 0.3f

__device__ __forceinline__ float limit_period_f(float v) {
    return v - floorf(v / TWO_PI_F + 0.5f) * TWO_PI_F;
}

// ---------------------------------------------------------------------------
// Clip polygon (px,py,cnt) by half-plane left of edge (a->b).
// Fully unrolled, register-only (no runtime-indexed array writes).
// ---------------------------------------------------------------------------
__device__ __forceinline__ void clip_edge(float (&px)[8], float (&py)[8], int &cnt,
                                          float axp, float ayp, float bxp, float byp) {
    float ex = bxp - axp, ey = byp - ayp;
    float d[8];
#pragma unroll
    for (int v = 0; v < 8; ++v)
        d[v] = ex * (py[v] - ayp) - ey * (px[v] - axp);

    float cxv[16], cyv[16];
    bool fl[16];
#pragma unroll
    for (int v = 0; v < 8; ++v) {
        bool valid = v < cnt;
        bool wrap = !(v + 1 < cnt);              // reference: nxt = idx+1<cnt ? idx+1 : 0
        float p2x = wrap ? px[0] : px[(v + 1) & 7];
        float p2y = wrap ? py[0] : py[(v + 1) & 7];
        float d2v = wrap ? d[0] : d[(v + 1) & 7];
        float d1v = d[v];
        bool in1 = d1v >= 0.0f, in2 = d2v >= 0.0f;
        fl[2 * v] = in1 && valid;
        cxv[2 * v] = px[v];
        cyv[2 * v] = py[v];
        fl[2 * v + 1] = (in1 != in2) && valid;
        float den = d1v - d2v;
        float t = d1v / (fabsf(den) > 1e-8f ? den : 1.0f);
        cxv[2 * v + 1] = px[v] + t * (p2x - px[v]);
        cyv[2 * v + 1] = py[v] + t * (p2y - py[v]);
    }

    // Compact candidates into output slots with an unrolled select network.
    int pos = 0;
    float ox[8], oy[8];
#pragma unroll
    for (int o = 0; o < 8; ++o) { ox[o] = 0.0f; oy[o] = 0.0f; }
#pragma unroll
    for (int c = 0; c < 16; ++c) {
#pragma unroll
        for (int o = 0; o < 8; ++o) {
            if (o > c) continue;                 // pos[c] <= c, compile-time prune
            if (fl[c] && pos == o) { ox[o] = cxv[c]; oy[o] = cyv[c]; }
        }
        pos += fl[c] ? 1 : 0;
    }
    cnt = pos > 8 ? 8 : pos;
#pragma unroll
    for (int v = 0; v < 8; ++v) { px[v] = ox[v]; py[v] = oy[v]; }
}

// ---------------------------------------------------------------------------
// Kernel 1: pairwise IoU3D > 0.3 adjacency bitmask. One thread per (i,j);
// wave = 64 consecutive j for one i -> one u64 adjacency word per wave.
// ---------------------------------------------------------------------------
__global__ __launch_bounds__(256) void iou_adj_kernel(const float* __restrict__ boxes,
                                                      unsigned long long* __restrict__ adj) {
    int t = blockIdx.x * 256 + threadIdx.x;
    int i = t >> 10;
    int j = t & 1023;
    const float* ba = boxes + i * 7;
    const float* bb = boxes + j * 7;
    float ax = ba[0], ay = ba[1], az = ba[2], al = ba[3], aw = ba[4], ah = ba[5];
    float bx = bb[0], by = bb[1], bz = bb[2], bl = bb[3], bw = bb[4], bh = bb[5];
    float tha = limit_period_f(ba[6]);
    float thb = limit_period_f(bb[6]);

    bool hit = false;
    float dx = ax - bx, dy = ay - by;
    float ra = 0.5f * sqrtf(al * al + aw * aw);
    float rb = 0.5f * sqrtf(bl * bl + bw * bw);
    float top = fminf(az + 0.5f * ah, bz + 0.5f * bh);
    float bot = fmaxf(az - 0.5f * ah, bz - 0.5f * bh);
    float hov = fmaxf(top - bot, 0.0f);
    float rr = ra + rb;
    // Exact reject: disjoint circumscribed circles or no height overlap => iou = 0.
    if (dx * dx + dy * dy <= rr * rr && hov > 0.0f) {
        float ca = cosf(tha), sa = sinf(tha);
        float cb = cosf(thb), sb = sinf(thb);

        float px[8], py[8];
        {   // corners of A: signs (0.5,-0.5),(0.5,0.5),(-0.5,0.5),(-0.5,-0.5)
            float hx = 0.5f * al, hy = 0.5f * aw;
            float sxv[4] = { hx, hx, -hx, -hx };
            float syv[4] = { -hy, hy, hy, -hy };
#pragma unroll
            for (int k = 0; k < 4; ++k) {
                px[k] = sxv[k] * ca - syv[k] * sa + ax;
                py[k] = sxv[k] * sa + syv[k] * ca + ay;
            }
#pragma unroll
            for (int k = 4; k < 8; ++k) { px[k] = 0.0f; py[k] = 0.0f; }
        }
        float qx[4], qy[4];
        {
            float hx = 0.5f * bl, hy = 0.5f * bw;
            float sxv[4] = { hx, hx, -hx, -hx };
            float syv[4] = { -hy, hy, hy, -hy };
#pragma unroll
            for (int k = 0; k < 4; ++k) {
                qx[k] = sxv[k] * cb - syv[k] * sb + bx;
                qy[k] = sxv[k] * sb + syv[k] * cb + by;
            }
        }
        int cnt = 4;
#pragma unroll
        for (int k = 0; k < 4; ++k)
            clip_edge(px, py, cnt, qx[k], qy[k], qx[(k + 1) & 3], qy[(k + 1) & 3]);

        // shoelace area over cnt vertices
        float s2 = 0.0f;
#pragma unroll
        for (int v = 0; v < 8; ++v) {
            bool valid = v < cnt;
            bool wrap = !(v + 1 < cnt);
            float p2x = wrap ? px[0] : px[(v + 1) & 7];
            float p2y = wrap ? py[0] : py[(v + 1) & 7];
            float cr = px[v] * p2y - p2x * py[v];
            s2 += valid ? cr : 0.0f;
        }
        float area = 0.5f * fabsf(s2);
        float inter = area * hov;
        float va = al * aw * ah, vb = bl * bw * bh;
        float iou = inter / fmaxf(va + vb - inter, 1e-6f);
        hit = iou > IOU_THR_F;
    }
    unsigned long long bal = __ballot(hit);
    if ((threadIdx.x & 63) == 0)
        adj[t >> 6] = bal;
}

// ---------------------------------------------------------------------------
// Kernel 2: sequential greedy clustering as an ordered scan, with the
// adjacency matrix staged in LDS (128 KiB exactly) so the serial chain never
// touches global memory. 1024 threads cooperatively fill LDS; wave 0 scans.
// All per-stage state is NAMED SCALARS (s0..s7, c0..c15) -- no arrays, so the
// compiler cannot demote anything to scratch (round-3 lesson: VGPR_Count=28
// proved the array version spilled).
// Seed sequence equivalence: the unassigned set only loses bits, so
// "first = argmax(unassigned)" is strictly increasing -> ordered scan r=0..1023.
// ---------------------------------------------------------------------------
#define UPDALL                                         \
    c0  = (bits & 0x0001u) ? cur : c0;                 \
    c1  = (bits & 0x0002u) ? cur : c1;                 \
    c2  = (bits & 0x0004u) ? cur : c2;                 \
    c3  = (bits & 0x0008u) ? cur : c3;                 \
    c4  = (bits & 0x0010u) ? cur : c4;                 \
    c5  = (bits & 0x0020u) ? cur : c5;                 \
    c6  = (bits & 0x0040u) ? cur : c6;                 \
    c7  = (bits & 0x0080u) ? cur : c7;                 \
    c8  = (bits & 0x0100u) ? cur : c8;                 \
    c9  = (bits & 0x0200u) ? cur : c9;                 \
    c10 = (bits & 0x0400u) ? cur : c10;                \
    c11 = (bits & 0x0800u) ? cur : c11;                \
    c12 = (bits & 0x1000u) ? cur : c12;                \
    c13 = (bits & 0x2000u) ? cur : c13;                \
    c14 = (bits & 0x4000u) ? cur : c14;                \
    c15 = (bits & 0x8000u) ? cur : c15;

#define STEP(REG, D)                                                        \
    {                                                                       \
        unsigned long long w = REG;                                         \
        int rr = r + (D);                                                   \
        REG = sp[(((rr + 8) & 1023) << 4)];                                 \
        bool seed = (lane == (rr >> 4)) && ((um >> (rr & 15)) & 1u);        \
        if (__ballot(seed)) {                                               \
            unsigned int bits = (unsigned int)(w >> shft) & 0xFFFFu;        \
            um &= ~bits;                                                    \
            UPDALL                                                          \
            ++cur;                                                          \
        }                                                                   \
    }

__global__ __launch_bounds__(1024) void cluster_kernel(const unsigned long long* __restrict__ adj,
                                                       int* __restrict__ ci,
                                                       int* __restrict__ nclust_out) {
    __shared__ unsigned long long sadj[NBOX * 16];   // 131072 B = 128 KiB exactly
    int tid = threadIdx.x;
    // Cooperative global->LDS fill: 16 waves, coalesced.
#pragma unroll
    for (int jj = 0; jj < 16; ++jj)
        sadj[jj * 1024 + tid] = adj[jj * 1024 + tid];
    __syncthreads();
    if (tid >= 64) return;                           // wave 0 scans alone

    int lane = tid;
    int widx = lane >> 2;            // which u64 word of a row this lane reads
    int shft = (lane & 3) * 16;      // 16-bit subfield within that word
    const unsigned long long* sp = &sadj[widx];

    int c0 = 0, c1 = 0, c2 = 0, c3 = 0, c4 = 0, c5 = 0, c6 = 0, c7 = 0;
    int c8 = 0, c9 = 0, c10 = 0, c11 = 0, c12 = 0, c13 = 0, c14 = 0, c15 = 0;
    unsigned int um = 0xFFFFu;       // unassigned bits for this lane's 16 boxes
    int cur = 1;

    // 8-stage pipeline prologue: rows 0..7
    unsigned long long s0 = sp[0 << 4], s1 = sp[1 << 4], s2 = sp[2 << 4], s3 = sp[3 << 4];
    unsigned long long s4 = sp[4 << 4], s5 = sp[5 << 4], s6 = sp[6 << 4], s7 = sp[7 << 4];

    for (int r = 0; r < NBOX; r += 8) {
        STEP(s0, 0) STEP(s1, 1) STEP(s2, 2) STEP(s3, 3)
        STEP(s4, 4) STEP(s5, 5) STEP(s6, 6) STEP(s7, 7)
    }

    int base = lane * 16;
    ci[base + 0] = c0;   ci[base + 1] = c1;   ci[base + 2] = c2;   ci[base + 3] = c3;
    ci[base + 4] = c4;   ci[base + 5] = c5;   ci[base + 6] = c6;   ci[base + 7] = c7;
    ci[base + 8] = c8;   ci[base + 9] = c9;   ci[base + 10] = c10; ci[base + 11] = c11;
    ci[base + 12] = c12; ci[base + 13] = c13; ci[base + 14] = c14; ci[base + 15] = c15;
    if (lane == 0)
        *nclust_out = cur - 1;       // number of non-empty cluster ids
}

// ---------------------------------------------------------------------------
// Kernel 3: cluster fusion. Block = 256 threads = 4 waves; wave w handles
// cid = blockIdx*4 + w + 1. Boxes (heading limited), scores, ci in LDS.
// Block-level early exit when all 4 cids exceed n_clusters (block-uniform,
// skips the 36 KB LDS staging); per-wave early exit for empty cids otherwise.
// Three passes mirror the reference exactly.
// ---------------------------------------------------------------------------
__global__ __launch_bounds__(256) void fusion_kernel(const float* __restrict__ boxes,
                                                     const float* __restrict__ scores,
                                                     const int* __restrict__ ci,
                                                     const int* __restrict__ nclust_p,
                                                     float* __restrict__ out) {
    __shared__ float sb[NBOX][7];
    __shared__ float ss[NBOX];
    __shared__ int   sc[NBOX];
    int tid = threadIdx.x;
    int nclust = *nclust_p;                       // block-uniform scalar load

    if (blockIdx.x * 4 + 1 > nclust) {            // all 4 cids empty: zero rows, skip staging
        if (tid < 28) {
            out[blockIdx.x * 28 + tid] = 0.0f;    // 4 cids x 7 floats
        }
        return;
    }

    for (int idx = tid; idx < NBOX * 7; idx += 256) {
        float v = boxes[idx];
        int col = idx % 7;
        if (col == 6) v = limit_period_f(v);
        sb[idx / 7][col] = v;
    }
    for (int b = tid; b < NBOX; b += 256) {
        ss[b] = scores[b];
        sc[b] = ci[b];
    }
    __syncthreads();

    int wave = tid >> 6;
    int lane = tid & 63;
    int cid = blockIdx.x * 4 + wave + 1;

    // ---- pass 1: argmax of masked scores (first occurrence on ties) ----
    float bv = -INFINITY;
    int bi = 0;
    for (int c = 0; c < 16; ++c) {
        int b = c * 64 + lane;
        float v = (sc[b] == cid) ? ss[b] : -INFINITY;
        if (v > bv) { bv = v; bi = b; }          // ascending b => keeps first max
    }
#pragma unroll
    for (int off = 32; off > 0; off >>= 1) {
        float ov = __shfl_xor(bv, off);
        int   oi = __shfl_xor(bi, off);
        if (ov > bv || (ov == bv && oi < bi)) { bv = ov; bi = oi; }
    }
    float* o = out + (cid - 1) * 7;
    if (!(bv > -INFINITY)) {                     // empty cluster: all-zero row
        if (lane == 0) {
#pragma unroll
            for (int jj = 0; jj < 7; ++jj) o[jj] = 0.0f;
        }
        return;
    }
    float d0 = sb[bi][6];

    // ---- pass 2: flip decision + score sum ----
    float sgt = 0.0f, sngt = 0.0f, ssum = 0.0f;
    for (int c = 0; c < 16; ++c) {
        int b = c * 64 + lane;
        float s = (sc[b] == cid) ? ss[b] : 0.0f;
        float diff = fabsf(sb[b][6] - d0);
        diff = (diff > PI_F) ? (TWO_PI_F - diff) : diff;
        bool gt = diff > HALF_PI_F;
        sgt += gt ? s : 0.0f;
        sngt += gt ? 0.0f : s;
        ssum += s;
    }
#pragma unroll
    for (int off = 32; off > 0; off >>= 1) {
        sgt  += __shfl_xor(sgt, off);
        sngt += __shfl_xor(sngt, off);
        ssum += __shfl_xor(ssum, off);
    }
    bool flip = (sgt <= sngt);
    float inv = ssum;                            // non-empty => ssum > 0

    // ---- pass 3: weighted sums (sn applied per-box like the reference) ----
    float sint = 0.0f, cost = 0.0f;
    float acc[6] = { 0.0f, 0.0f, 0.0f, 0.0f, 0.0f, 0.0f };
    for (int c = 0; c < 16; ++c) {
        int b = c * 64 + lane;
        float s = (sc[b] == cid) ? ss[b] : 0.0f;
        float sn = s / inv;
        float dH = sb[b][6];
        float diff = fabsf(dH - d0);
        diff = (diff > PI_F) ? (TWO_PI_F - diff) : diff;
        bool gt = diff > HALF_PI_F;
        bool cond = flip ? gt : !gt;
        float dd = cond ? (dH + PI_F) : dH;
        dd = limit_period_f(dd);
        sint += sinf(dd) * sn;
        cost += cosf(dd) * sn;
#pragma unroll
        for (int jj = 0; jj < 6; ++jj)
            acc[jj] += sb[b][jj] * sn;
    }
#pragma unroll
    for (int off = 32; off > 0; off >>= 1) {
        sint += __shfl_xor(sint, off);
        cost += __shfl_xor(cost, off);
#pragma unroll
        for (int jj = 0; jj < 6; ++jj)
            acc[jj] += __shfl_xor(acc[jj], off);
    }

    if (lane == 0) {
#pragma unroll
        for (int jj = 0; jj < 6; ++jj) o[jj] = acc[jj];
        o[6] = atan2f(sint, cost);
    }
}

extern "C" void kernel_launch(void* const* d_in, const int* in_sizes, int n_in,
                              void* d_out, int out_size, void* d_ws, size_t ws_size,
                              hipStream_t stream) {
    const float* boxes  = (const float*)d_in[0];   // (1024,7) f32
    const float* scores = (const float*)d_in[1];   // (1024,)  f32
    unsigned long long* adj = (unsigned long long*)d_ws;              // 1024*16 u64 = 128 KB
    int* ci = (int*)((char*)d_ws + (size_t)NBOX * 16 * sizeof(unsigned long long));
    int* nclust = ci + NBOX;                       // one int after ci
    float* out = (float*)d_out;                    // (1024,7) f32

    iou_adj_kernel<<<(NBOX * NBOX) / 256, 256, 0, stream>>>(boxes, adj);
    cluster_kernel<<<1, 1024, 0, stream>>>(adj, ci, nclust);
    fusion_kernel<<<NBOX / 4, 256, 0, stream>>>(boxes, scores, ci, nclust, out);
}